// Round 5
// baseline (704.839 us; speedup 1.0000x reference)
//
#include <hip/hip_runtime.h>
#include <hip/hip_bf16.h>

#define N_NODES   50000
#define N_EDGES   600000
#define HID       128
#define N_LAYERS  4
#define N_GRAPHS  128
#define N_CLASSES 10
#define BN_EPS    1e-5f

#define TILE_R 64
#define KC     32
#define RSPLIT 8
#define SCAN_B 196          // ceil(50000/256)
#define AS_LD  132          // As leading dim: float4-aligned, 2-way-max bank conflicts

// ---------------- workspace layout (in 4-byte elements) ----------------
#define OFF_WMT   0u                         // 5 * 16384 masked+transposed weights [k][c]
#define OFF_H     81920u                     // 50000*128
#define OFF_Z     (OFF_H   + 6400000u)
#define OFF_AGG   (OFF_Z   + 6400000u)       // (unused after fusion; kept for layout stability)
#define OFF_ZERO  (OFF_AGG + 6400000u)       // start of zero-initialized region
#define OFF_CSUM  OFF_ZERO                   // [4][2][128] = 1024 f
#define OFF_SUMS  (OFF_CSUM + 1024u)         // [128][128]  = 16384 f
#define OFF_DEG   (OFF_SUMS + 16384u)        // [50000] int
#define ZERO_N    (1024u + 16384u + 50000u)  // 67408 elements
#define OFF_OFFS  (OFF_ZERO + ZERO_N)        // [50001] int (padded to 50004)
#define OFF_POS   (OFF_OFFS + 50004u)        // [50000] int
#define OFF_ESRC  (OFF_POS  + 50000u)        // [600000] int
#define OFF_GST   (OFF_ESRC + 600000u)       // [129] int graph boundaries (pad 132)
#define OFF_BSUM  (OFF_GST  + 132u)          // [196] int block sums
#define OFF_TOT   (OFF_BSUM + 196u)          // [1] int total

__global__ __launch_bounds__(256) void zero_kernel(int* __restrict__ p, int n) {
    int i = blockIdx.x * 256 + threadIdx.x;
    if (i < n) p[i] = 0;
}

// masked + transposed weights: WmT[m][k][c] = W[m][c][k] * M[m][c][k]
__global__ __launch_bounds__(256) void wmask_kernel(
    const float* __restrict__ We, const float* __restrict__ Me,
    const float* __restrict__ Wl, const float* __restrict__ Ml,
    float* __restrict__ WmT)
{
    int i = blockIdx.x * 256 + threadIdx.x;
    if (i >= 5 * 16384) return;
    int m = i >> 14;
    int j = i & 16383;
    int c = j >> 7, k = j & 127;
    float w, msk;
    if (m == 0) { w = We[j]; msk = Me[j]; }
    else        { w = Wl[(m - 1) * 16384 + j]; msk = Ml[(m - 1) * 16384 + j]; }
    WmT[m * 16384 + k * 128 + c] = w * msk;
}

__global__ __launch_bounds__(256) void hist_kernel(const int* __restrict__ dst,
                                                   int* __restrict__ deg, int nE) {
    int i = blockIdx.x * 256 + threadIdx.x;
    if (i < nE) atomicAdd(&deg[dst[i]], 1);
}

// parallel scan, stage 1: per-block exclusive scan of deg -> off (temp), block sums -> bsum
__global__ __launch_bounds__(256) void scan1_kernel(const int* __restrict__ deg,
                                                    int* __restrict__ off,
                                                    int* __restrict__ bsum, int n) {
    __shared__ int s[256];
    int tid = threadIdx.x;
    int i = blockIdx.x * 256 + tid;
    int v = (i < n) ? deg[i] : 0;
    s[tid] = v;
    __syncthreads();
#pragma unroll
    for (int ofs = 1; ofs < 256; ofs <<= 1) {
        int t = (tid >= ofs) ? s[tid - ofs] : 0;
        __syncthreads();
        s[tid] += t;
        __syncthreads();
    }
    if (i < n) off[i] = s[tid] - v;                    // exclusive within block
    if (tid == 255) bsum[blockIdx.x] = s[255];
}

// stage 2: single block scans the block sums (nb <= 256), writes exclusive offsets + total
__global__ __launch_bounds__(256) void scan2_kernel(int* __restrict__ bsum,
                                                    int* __restrict__ total, int nb) {
    __shared__ int s[256];
    int tid = threadIdx.x;
    int v = (tid < nb) ? bsum[tid] : 0;
    s[tid] = v;
    __syncthreads();
#pragma unroll
    for (int ofs = 1; ofs < 256; ofs <<= 1) {
        int t = (tid >= ofs) ? s[tid - ofs] : 0;
        __syncthreads();
        s[tid] += t;
        __syncthreads();
    }
    if (tid < nb) bsum[tid] = s[tid] - v;              // exclusive block offsets
    if (tid == 255) *total = s[255];
}

// stage 3: add block offsets, produce final off + pos; write off[n]
__global__ __launch_bounds__(256) void scan3_kernel(int* __restrict__ off,
                                                    const int* __restrict__ bsum,
                                                    const int* __restrict__ total,
                                                    int* __restrict__ pos, int n) {
    int i = blockIdx.x * 256 + threadIdx.x;
    if (i < n) {
        int o = off[i] + bsum[blockIdx.x];
        off[i] = o;
        pos[i] = o;
    }
    if (i == 0) off[n] = *total;
}

__global__ __launch_bounds__(256) void fill_kernel(const int* __restrict__ src,
                                                   const int* __restrict__ dst,
                                                   int* __restrict__ pos,
                                                   int* __restrict__ esrc, int nE) {
    int i = blockIdx.x * 256 + threadIdx.x;
    if (i < nE) {
        int p = atomicAdd(&pos[dst[i]], 1);
        esrc[p] = src[i];
    }
}

// graph boundaries from sorted gid: g_start[g] = first node of graph g; g_start[G]=n
__global__ __launch_bounds__(256) void bounds_kernel(const int* __restrict__ gid,
                                                     int* __restrict__ g_start, int nN) {
    int i = blockIdx.x * 256 + threadIdx.x;
    if (i >= nN) return;
    int g = gid[i];
    if (i == 0) {
        for (int x = 0; x <= g; ++x) g_start[x] = 0;
    } else {
        int gp = gid[i - 1];
        for (int x = gp + 1; x <= g; ++x) g_start[x] = i;
    }
    if (i == nN - 1) {
        for (int x = g + 1; x <= N_GRAPHS; ++x) g_start[x] = nN;
    }
}

// dense GEMM (used for the embedding layer): Z = A @ WmT + bias, optional snorm/colsum
__global__ __launch_bounds__(256) void gemm_kernel(
    const float* __restrict__ A, const float* __restrict__ WmT,
    const float* __restrict__ bias, const float* __restrict__ snorm,
    float* __restrict__ Z, float* __restrict__ colsum, int nRows)
{
    __shared__ float Ws[KC][128];
    __shared__ float As[TILE_R][KC + 1];
    int tid = threadIdx.x;
    int tx = tid & 15;       // 16 col groups
    int ty = tid >> 4;       // 16 row groups (4 rows each)
    int r0 = blockIdx.x * TILE_R;

    float acc[4][8];
#pragma unroll
    for (int i = 0; i < 4; ++i)
#pragma unroll
        for (int j = 0; j < 8; ++j) acc[i][j] = 0.f;

    for (int k0 = 0; k0 < 128; k0 += KC) {
        {
            const float4* srcv = (const float4*)(WmT + k0 * 128);
            float4* dstv = (float4*)&Ws[0][0];
#pragma unroll
            for (int it = 0; it < 4; ++it) {
                int f4 = tid + it * 256;
                dstv[f4] = srcv[f4];
            }
        }
        {
            int rr = tid >> 3;      // 0..31
            int l8 = tid & 7;       // 0..7
#pragma unroll
            for (int it = 0; it < 2; ++it) {
                int r = rr + it * 32;
                int gr = r0 + r;
                float4 v = make_float4(0.f, 0.f, 0.f, 0.f);
                if (gr < nRows) v = *(const float4*)(A + (size_t)gr * 128 + k0 + l8 * 4);
                As[r][l8 * 4 + 0] = v.x;
                As[r][l8 * 4 + 1] = v.y;
                As[r][l8 * 4 + 2] = v.z;
                As[r][l8 * 4 + 3] = v.w;
            }
        }
        __syncthreads();
#pragma unroll 4
        for (int k = 0; k < KC; ++k) {
            float a0 = As[ty * 4 + 0][k];
            float a1 = As[ty * 4 + 1][k];
            float a2 = As[ty * 4 + 2][k];
            float a3 = As[ty * 4 + 3][k];
            float4 w0 = *(const float4*)&Ws[k][tx * 4];
            float4 w1 = *(const float4*)&Ws[k][64 + tx * 4];
            acc[0][0] += a0 * w0.x; acc[0][1] += a0 * w0.y; acc[0][2] += a0 * w0.z; acc[0][3] += a0 * w0.w;
            acc[0][4] += a0 * w1.x; acc[0][5] += a0 * w1.y; acc[0][6] += a0 * w1.z; acc[0][7] += a0 * w1.w;
            acc[1][0] += a1 * w0.x; acc[1][1] += a1 * w0.y; acc[1][2] += a1 * w0.z; acc[1][3] += a1 * w0.w;
            acc[1][4] += a1 * w1.x; acc[1][5] += a1 * w1.y; acc[1][6] += a1 * w1.z; acc[1][7] += a1 * w1.w;
            acc[2][0] += a2 * w0.x; acc[2][1] += a2 * w0.y; acc[2][2] += a2 * w0.z; acc[2][3] += a2 * w0.w;
            acc[2][4] += a2 * w1.x; acc[2][5] += a2 * w1.y; acc[2][6] += a2 * w1.z; acc[2][7] += a2 * w1.w;
            acc[3][0] += a3 * w0.x; acc[3][1] += a3 * w0.y; acc[3][2] += a3 * w0.z; acc[3][3] += a3 * w0.w;
            acc[3][4] += a3 * w1.x; acc[3][5] += a3 * w1.y; acc[3][6] += a3 * w1.z; acc[3][7] += a3 * w1.w;
        }
        __syncthreads();
    }

    int c0 = tx * 4;
    float bl[8];
#pragma unroll
    for (int j = 0; j < 4; ++j) {
        bl[j]     = bias[c0 + j];
        bl[4 + j] = bias[64 + c0 + j];
    }
#pragma unroll
    for (int i = 0; i < 4; ++i) {
        int r = r0 + ty * 4 + i;
        if (r < nRows) {
            float sn = snorm ? snorm[r] : 1.0f;
            float4 o0, o1;
            o0.x = (acc[i][0] + bl[0]) * sn;
            o0.y = (acc[i][1] + bl[1]) * sn;
            o0.z = (acc[i][2] + bl[2]) * sn;
            o0.w = (acc[i][3] + bl[3]) * sn;
            o1.x = (acc[i][4] + bl[4]) * sn;
            o1.y = (acc[i][5] + bl[5]) * sn;
            o1.z = (acc[i][6] + bl[6]) * sn;
            o1.w = (acc[i][7] + bl[7]) * sn;
            *(float4*)(Z + (size_t)r * 128 + c0)      = o0;
            *(float4*)(Z + (size_t)r * 128 + 64 + c0) = o1;
        }
    }
    (void)colsum;
}

// fused: gather-aggregate 64 node rows into LDS, then GEMM vs WmT, epilogue snorm+colsum
__global__ __launch_bounds__(256) void agg_gemm_kernel(
    const float* __restrict__ H, const int* __restrict__ off,
    const int* __restrict__ esrc,
    const float* __restrict__ WmT, const float* __restrict__ bias,
    const float* __restrict__ snorm,
    float* __restrict__ Z, float* __restrict__ colsum, int nRows)
{
    __shared__ float Ws[KC][128];       // 16 KB
    __shared__ float As[TILE_R][AS_LD]; // 33.8 KB
    int tid = threadIdx.x;
    int r0 = blockIdx.x * TILE_R;

    // ---- phase 1: gather + aggregate into As ----
    {
        int wave   = tid >> 6;          // 0..3
        int halfid = (tid >> 5) & 1;    // 0..1
        int l4     = tid & 31;          // float4 lane within row
        const float4* H4 = (const float4*)H;
#pragma unroll
        for (int pass = 0; pass < 8; ++pass) {
            int rl = pass * 8 + wave * 2 + halfid;   // local row 0..63
            int node = r0 + rl;
            float4 a0 = make_float4(0.f, 0.f, 0.f, 0.f);
            float4 a1 = make_float4(0.f, 0.f, 0.f, 0.f);
            if (node < nRows) {
                int beg = off[node], end = off[node + 1];
                int e = beg;
                for (; e + 1 < end; e += 2) {
                    int s0 = esrc[e], s1 = esrc[e + 1];
                    float4 v0 = H4[(size_t)s0 * 32 + l4];
                    float4 v1 = H4[(size_t)s1 * 32 + l4];
                    a0.x += v0.x; a0.y += v0.y; a0.z += v0.z; a0.w += v0.w;
                    a1.x += v1.x; a1.y += v1.y; a1.z += v1.z; a1.w += v1.w;
                }
                if (e < end) {
                    float4 v0 = H4[(size_t)esrc[e] * 32 + l4];
                    a0.x += v0.x; a0.y += v0.y; a0.z += v0.z; a0.w += v0.w;
                }
            }
            a0.x += a1.x; a0.y += a1.y; a0.z += a1.z; a0.w += a1.w;
            *(float4*)&As[rl][l4 * 4] = a0;
        }
    }
    __syncthreads();

    // ---- phase 2: GEMM As @ WmT ----
    int tx = tid & 15;
    int ty = tid >> 4;
    float acc[4][8];
#pragma unroll
    for (int i = 0; i < 4; ++i)
#pragma unroll
        for (int j = 0; j < 8; ++j) acc[i][j] = 0.f;

    for (int k0 = 0; k0 < 128; k0 += KC) {
        {
            const float4* srcv = (const float4*)(WmT + k0 * 128);
            float4* dstv = (float4*)&Ws[0][0];
#pragma unroll
            for (int it = 0; it < 4; ++it) {
                int f4 = tid + it * 256;
                dstv[f4] = srcv[f4];
            }
        }
        __syncthreads();
#pragma unroll 4
        for (int k = 0; k < KC; ++k) {
            float a0 = As[ty * 4 + 0][k0 + k];
            float a1 = As[ty * 4 + 1][k0 + k];
            float a2 = As[ty * 4 + 2][k0 + k];
            float a3 = As[ty * 4 + 3][k0 + k];
            float4 w0 = *(const float4*)&Ws[k][tx * 4];
            float4 w1 = *(const float4*)&Ws[k][64 + tx * 4];
            acc[0][0] += a0 * w0.x; acc[0][1] += a0 * w0.y; acc[0][2] += a0 * w0.z; acc[0][3] += a0 * w0.w;
            acc[0][4] += a0 * w1.x; acc[0][5] += a0 * w1.y; acc[0][6] += a0 * w1.z; acc[0][7] += a0 * w1.w;
            acc[1][0] += a1 * w0.x; acc[1][1] += a1 * w0.y; acc[1][2] += a1 * w0.z; acc[1][3] += a1 * w0.w;
            acc[1][4] += a1 * w1.x; acc[1][5] += a1 * w1.y; acc[1][6] += a1 * w1.z; acc[1][7] += a1 * w1.w;
            acc[2][0] += a2 * w0.x; acc[2][1] += a2 * w0.y; acc[2][2] += a2 * w0.z; acc[2][3] += a2 * w0.w;
            acc[2][4] += a2 * w1.x; acc[2][5] += a2 * w1.y; acc[2][6] += a2 * w1.z; acc[2][7] += a2 * w1.w;
            acc[3][0] += a3 * w0.x; acc[3][1] += a3 * w0.y; acc[3][2] += a3 * w0.z; acc[3][3] += a3 * w0.w;
            acc[3][4] += a3 * w1.x; acc[3][5] += a3 * w1.y; acc[3][6] += a3 * w1.z; acc[3][7] += a3 * w1.w;
        }
        __syncthreads();
    }

    // ---- epilogue: bias, snorm, Z-store, colsum partials ----
    int c0 = tx * 4;
    float bl[8];
#pragma unroll
    for (int j = 0; j < 4; ++j) {
        bl[j]     = bias[c0 + j];
        bl[4 + j] = bias[64 + c0 + j];
    }
    float cs[8], cq[8];
#pragma unroll
    for (int j = 0; j < 8; ++j) { cs[j] = 0.f; cq[j] = 0.f; }

#pragma unroll
    for (int i = 0; i < 4; ++i) {
        int r = r0 + ty * 4 + i;
        if (r < nRows) {
            float sn = snorm[r];
            float4 o0, o1;
            float v;
            v = (acc[i][0] + bl[0]) * sn; o0.x = v; cs[0] += v; cq[0] += v * v;
            v = (acc[i][1] + bl[1]) * sn; o0.y = v; cs[1] += v; cq[1] += v * v;
            v = (acc[i][2] + bl[2]) * sn; o0.z = v; cs[2] += v; cq[2] += v * v;
            v = (acc[i][3] + bl[3]) * sn; o0.w = v; cs[3] += v; cq[3] += v * v;
            v = (acc[i][4] + bl[4]) * sn; o1.x = v; cs[4] += v; cq[4] += v * v;
            v = (acc[i][5] + bl[5]) * sn; o1.y = v; cs[5] += v; cq[5] += v * v;
            v = (acc[i][6] + bl[6]) * sn; o1.z = v; cs[6] += v; cq[6] += v * v;
            v = (acc[i][7] + bl[7]) * sn; o1.w = v; cs[7] += v; cq[7] += v * v;
            *(float4*)(Z + (size_t)r * 128 + c0)      = o0;
            *(float4*)(Z + (size_t)r * 128 + 64 + c0) = o1;
        }
    }

    {
        float* red = &Ws[0][0];  // 16*128 floats fits in Ws
        for (int round = 0; round < 2; ++round) {
            float* srcp = round ? cq : cs;
#pragma unroll
            for (int j = 0; j < 4; ++j) {
                red[ty * 128 + c0 + j]      = srcp[j];
                red[ty * 128 + 64 + c0 + j] = srcp[4 + j];
            }
            __syncthreads();
            if (tid < 128) {
                float s = 0.f;
#pragma unroll
                for (int t = 0; t < 16; ++t) s += red[t * 128 + tid];
                atomicAdd(&colsum[round * 128 + tid], s);
            }
            __syncthreads();
        }
    }
}

// H += relu((Z - mu)*rsqrt(var+eps)*gamma + beta); BN params computed inline from csum
__global__ __launch_bounds__(256) void apply_kernel(const float* __restrict__ Z,
                                                    const float* __restrict__ csum,
                                                    const float* __restrict__ gamma,
                                                    const float* __restrict__ beta,
                                                    float* __restrict__ H, int n4, int layer) {
    int i = blockIdx.x * 256 + threadIdx.x;
    if (i >= n4) return;
    int c4 = i & 31;
    const float invN = 1.0f / (float)N_NODES;
    float4 s  = ((const float4*)(csum  + layer * 256))[c4];
    float4 q  = ((const float4*)(csum  + layer * 256 + 128))[c4];
    float4 g  = ((const float4*)(gamma + layer * 128))[c4];
    float4 be = ((const float4*)(beta  + layer * 128))[c4];
    float4 z = ((const float4*)Z)[i];
    float4 h = ((float4*)H)[i];
    float mu, var, sc, sh;
    mu = s.x * invN; var = q.x * invN - mu * mu; sc = g.x * rsqrtf(var + BN_EPS); sh = be.x - mu * sc;
    h.x += fmaxf(z.x * sc + sh, 0.f);
    mu = s.y * invN; var = q.y * invN - mu * mu; sc = g.y * rsqrtf(var + BN_EPS); sh = be.y - mu * sc;
    h.y += fmaxf(z.y * sc + sh, 0.f);
    mu = s.z * invN; var = q.z * invN - mu * mu; sc = g.z * rsqrtf(var + BN_EPS); sh = be.z - mu * sc;
    h.z += fmaxf(z.z * sc + sh, 0.f);
    mu = s.w * invN; var = q.w * invN - mu * mu; sc = g.w * rsqrtf(var + BN_EPS); sh = be.w - mu * sc;
    h.w += fmaxf(z.w * sc + sh, 0.f);
    ((float4*)H)[i] = h;
}

// dense per-graph reduction using sorted-gid boundaries
__global__ __launch_bounds__(256) void readout2_kernel(const float* __restrict__ H,
                                                       const int* __restrict__ g_start,
                                                       float* __restrict__ sums) {
    int g     = blockIdx.x / RSPLIT;
    int chunk = blockIdx.x % RSPLIT;
    int beg = g_start[g], end = g_start[g + 1];
    int col  = threadIdx.x & 127;
    int half = threadIdx.x >> 7;
    float acc = 0.f;
    for (int r = beg + chunk * 2 + half; r < end; r += RSPLIT * 2) {
        acc += H[(size_t)r * 128 + col];
    }
    if (acc != 0.f || half == 0)
        atomicAdd(&sums[g * 128 + col], acc);
}

__global__ __launch_bounds__(128) void final_kernel(const float* __restrict__ sums,
                                                    const int* __restrict__ g_start,
                                                    const float* __restrict__ roW,
                                                    const float* __restrict__ rob,
                                                    float* __restrict__ out) {
    __shared__ float row[128];
    int g = blockIdx.x;
    int t = threadIdx.x;
    float c = fmaxf((float)(g_start[g + 1] - g_start[g]), 1.0f);
    row[t] = sums[g * 128 + t] / c;
    __syncthreads();
    if (t < N_CLASSES) {
        float s = rob[t];
        for (int k = 0; k < 128; ++k) s += row[k] * roW[t * 128 + k];
        out[g * N_CLASSES + t] = s;
    }
}

extern "C" void kernel_launch(void* const* d_in, const int* in_sizes, int n_in,
                              void* d_out, int out_size, void* d_ws, size_t ws_size,
                              hipStream_t stream) {
    const float* h0      = (const float*)d_in[0];
    const float* snorm   = (const float*)d_in[1];
    const int*   src     = (const int*)d_in[2];
    const int*   dst     = (const int*)d_in[3];
    const int*   gid     = (const int*)d_in[4];
    const float* embedW  = (const float*)d_in[5];
    const float* embedM  = (const float*)d_in[6];
    const float* embedB  = (const float*)d_in[7];
    const float* layerW  = (const float*)d_in[8];
    const float* layerM  = (const float*)d_in[9];
    const float* layerB  = (const float*)d_in[10];
    const float* gamma   = (const float*)d_in[11];
    const float* beta    = (const float*)d_in[12];
    const float* roW     = (const float*)d_in[13];
    const float* rob     = (const float*)d_in[14];
    float* out = (float*)d_out;

    float* ws   = (float*)d_ws;
    float* wmT  = ws + OFF_WMT;
    float* H    = ws + OFF_H;
    float* Z    = ws + OFF_Z;
    float* csum = ws + OFF_CSUM;
    float* sums = ws + OFF_SUMS;
    int*   deg  = (int*)(ws + OFF_DEG);
    int*   offs = (int*)(ws + OFF_OFFS);
    int*   pos  = (int*)(ws + OFF_POS);
    int*   esrc = (int*)(ws + OFF_ESRC);
    int*   gst  = (int*)(ws + OFF_GST);
    int*   bsum = (int*)(ws + OFF_BSUM);
    int*   tot  = (int*)(ws + OFF_TOT);

    // zero: colsum + readout sums + deg (single contiguous region)
    zero_kernel<<<(ZERO_N + 255) / 256, 256, 0, stream>>>((int*)(ws + OFF_ZERO), (int)ZERO_N);
    // masked + transposed weights
    wmask_kernel<<<(5 * 16384 + 255) / 256, 256, 0, stream>>>(embedW, embedM, layerW, layerM, wmT);
    // CSR build (once per call, reused by all 4 layers)
    hist_kernel<<<(N_EDGES + 255) / 256, 256, 0, stream>>>(dst, deg, N_EDGES);
    scan1_kernel<<<SCAN_B, 256, 0, stream>>>(deg, offs, bsum, N_NODES);
    scan2_kernel<<<1, 256, 0, stream>>>(bsum, tot, SCAN_B);
    scan3_kernel<<<SCAN_B, 256, 0, stream>>>(offs, bsum, tot, pos, N_NODES);
    fill_kernel<<<(N_EDGES + 255) / 256, 256, 0, stream>>>(src, dst, pos, esrc, N_EDGES);
    // graph boundaries (sorted gid)
    bounds_kernel<<<(N_NODES + 255) / 256, 256, 0, stream>>>(gid, gst, N_NODES);

    const int gemm_grid = (N_NODES + TILE_R - 1) / TILE_R;
    // embedding: H = h0 @ (embed_W*mask)^T + embed_b
    gemm_kernel<<<gemm_grid, 256, 0, stream>>>(h0, wmT, embedB, nullptr, H, nullptr, N_NODES);

    for (int l = 0; l < N_LAYERS; ++l) {
        agg_gemm_kernel<<<gemm_grid, 256, 0, stream>>>(H, offs, esrc,
                                                       wmT + (1 + l) * 16384,
                                                       layerB + l * 128, snorm,
                                                       Z, csum + l * 256, N_NODES);
        apply_kernel<<<(N_NODES * HID / 4) / 256, 256, 0, stream>>>(
            Z, csum, gamma, beta, H, N_NODES * HID / 4, l);
    }

    readout2_kernel<<<N_GRAPHS * RSPLIT, 256, 0, stream>>>(H, gst, sums);
    final_kernel<<<N_GRAPHS, 128, 0, stream>>>(sums, gst, roW, rob, out);
}

// Round 6
// 588.680 us; speedup vs baseline: 1.1973x; 1.1973x over previous
//
#include <hip/hip_runtime.h>
#include <hip/hip_bf16.h>

#define N_NODES   50000
#define N_EDGES   600000
#define HID       128
#define N_LAYERS  4
#define N_GRAPHS  128
#define N_CLASSES 10
#define BN_EPS    1e-5f

#define TILE_R 64
#define KC     32
#define RSPLIT 8
#define SCAN_B 196          // ceil(50000/256)

// ---------------- workspace layout (in 4-byte elements) ----------------
#define OFF_WMT   0u                         // 5 * 16384 masked+transposed weights [k][c]
#define OFF_H     81920u                     // 50000*128
#define OFF_Z     (OFF_H   + 6400000u)
#define OFF_AGG   (OFF_Z   + 6400000u)       // aggregate output [50000][128]
#define OFF_ZERO  (OFF_AGG + 6400000u)       // start of zero-initialized region
#define OFF_CSUM  OFF_ZERO                   // [4][2][128] = 1024 f
#define OFF_SUMS  (OFF_CSUM + 1024u)         // [128][128]  = 16384 f
#define OFF_DEG   (OFF_SUMS + 16384u)        // [50000] int
#define ZERO_N    (1024u + 16384u + 50000u)  // 67408 elements
#define OFF_OFFS  (OFF_ZERO + ZERO_N)        // [50001] int (padded to 50004)
#define OFF_POS   (OFF_OFFS + 50004u)        // [50000] int
#define OFF_ESRC  (OFF_POS  + 50000u)        // [600000] int
#define OFF_GST   (OFF_ESRC + 600000u)       // [129] int graph boundaries (pad 132)
#define OFF_BSUM  (OFF_GST  + 132u)          // [196] int block sums
#define OFF_TOT   (OFF_BSUM + 196u)          // [1] int total

__global__ __launch_bounds__(256) void zero_kernel(int* __restrict__ p, int n) {
    int i = blockIdx.x * 256 + threadIdx.x;
    if (i < n) p[i] = 0;
}

// masked + transposed weights: WmT[m][k][c] = W[m][c][k] * M[m][c][k]
__global__ __launch_bounds__(256) void wmask_kernel(
    const float* __restrict__ We, const float* __restrict__ Me,
    const float* __restrict__ Wl, const float* __restrict__ Ml,
    float* __restrict__ WmT)
{
    int i = blockIdx.x * 256 + threadIdx.x;
    if (i >= 5 * 16384) return;
    int m = i >> 14;
    int j = i & 16383;
    int c = j >> 7, k = j & 127;
    float w, msk;
    if (m == 0) { w = We[j]; msk = Me[j]; }
    else        { w = Wl[(m - 1) * 16384 + j]; msk = Ml[(m - 1) * 16384 + j]; }
    WmT[m * 16384 + k * 128 + c] = w * msk;
}

__global__ __launch_bounds__(256) void hist_kernel(const int* __restrict__ dst,
                                                   int* __restrict__ deg, int nE) {
    int i = blockIdx.x * 256 + threadIdx.x;
    if (i < nE) atomicAdd(&deg[dst[i]], 1);
}

// parallel scan, stage 1: per-block exclusive scan of deg -> off (temp), block sums -> bsum
__global__ __launch_bounds__(256) void scan1_kernel(const int* __restrict__ deg,
                                                    int* __restrict__ off,
                                                    int* __restrict__ bsum, int n) {
    __shared__ int s[256];
    int tid = threadIdx.x;
    int i = blockIdx.x * 256 + tid;
    int v = (i < n) ? deg[i] : 0;
    s[tid] = v;
    __syncthreads();
#pragma unroll
    for (int ofs = 1; ofs < 256; ofs <<= 1) {
        int t = (tid >= ofs) ? s[tid - ofs] : 0;
        __syncthreads();
        s[tid] += t;
        __syncthreads();
    }
    if (i < n) off[i] = s[tid] - v;                    // exclusive within block
    if (tid == 255) bsum[blockIdx.x] = s[255];
}

// stage 2: single block scans the block sums (nb <= 256), writes exclusive offsets + total
__global__ __launch_bounds__(256) void scan2_kernel(int* __restrict__ bsum,
                                                    int* __restrict__ total, int nb) {
    __shared__ int s[256];
    int tid = threadIdx.x;
    int v = (tid < nb) ? bsum[tid] : 0;
    s[tid] = v;
    __syncthreads();
#pragma unroll
    for (int ofs = 1; ofs < 256; ofs <<= 1) {
        int t = (tid >= ofs) ? s[tid - ofs] : 0;
        __syncthreads();
        s[tid] += t;
        __syncthreads();
    }
    if (tid < nb) bsum[tid] = s[tid] - v;              // exclusive block offsets
    if (tid == 255) *total = s[255];
}

// stage 3: add block offsets, produce final off + pos; write off[n]
__global__ __launch_bounds__(256) void scan3_kernel(int* __restrict__ off,
                                                    const int* __restrict__ bsum,
                                                    const int* __restrict__ total,
                                                    int* __restrict__ pos, int n) {
    int i = blockIdx.x * 256 + threadIdx.x;
    if (i < n) {
        int o = off[i] + bsum[blockIdx.x];
        off[i] = o;
        pos[i] = o;
    }
    if (i == 0) off[n] = *total;
}

__global__ __launch_bounds__(256) void fill_kernel(const int* __restrict__ src,
                                                   const int* __restrict__ dst,
                                                   int* __restrict__ pos,
                                                   int* __restrict__ esrc, int nE) {
    int i = blockIdx.x * 256 + threadIdx.x;
    if (i < nE) {
        int p = atomicAdd(&pos[dst[i]], 1);
        esrc[p] = src[i];
    }
}

// graph boundaries from sorted gid: g_start[g] = first node of graph g; g_start[G]=n
__global__ __launch_bounds__(256) void bounds_kernel(const int* __restrict__ gid,
                                                     int* __restrict__ g_start, int nN) {
    int i = blockIdx.x * 256 + threadIdx.x;
    if (i >= nN) return;
    int g = gid[i];
    if (i == 0) {
        for (int x = 0; x <= g; ++x) g_start[x] = 0;
    } else {
        int gp = gid[i - 1];
        for (int x = gp + 1; x <= g; ++x) g_start[x] = i;
    }
    if (i == nN - 1) {
        for (int x = g + 1; x <= N_GRAPHS; ++x) g_start[x] = nN;
    }
}

// agg[n][:] = sum over incoming edges of H[src][:]
// 2 nodes per wave (float4 x 32 lanes = 512B/row), edge loop unrolled x4
// -> up to 8 independent row-streams in flight per wave (MLP, latency hiding)
__global__ __launch_bounds__(256) void aggregate_kernel(const float* __restrict__ H,
                                                        const int* __restrict__ off,
                                                        const int* __restrict__ esrc,
                                                        float* __restrict__ agg, int nN) {
    int wid  = (blockIdx.x * 256 + threadIdx.x) >> 6;   // global wave id
    int lane = threadIdx.x & 63;
    int half = lane >> 5;                               // 0/1: which node of the pair
    int l4   = lane & 31;                               // float4 lane within row
    int node = wid * 2 + half;
    if (node >= nN) return;
    int beg = off[node], end = off[node + 1];
    const float4* H4 = (const float4*)H;
    float4 a0 = make_float4(0.f, 0.f, 0.f, 0.f);
    float4 a1 = make_float4(0.f, 0.f, 0.f, 0.f);
    float4 a2 = make_float4(0.f, 0.f, 0.f, 0.f);
    float4 a3 = make_float4(0.f, 0.f, 0.f, 0.f);
    int e = beg;
    for (; e + 3 < end; e += 4) {
        int s0 = esrc[e], s1 = esrc[e + 1], s2 = esrc[e + 2], s3 = esrc[e + 3];
        float4 v0 = H4[(size_t)s0 * 32 + l4];
        float4 v1 = H4[(size_t)s1 * 32 + l4];
        float4 v2 = H4[(size_t)s2 * 32 + l4];
        float4 v3 = H4[(size_t)s3 * 32 + l4];
        a0.x += v0.x; a0.y += v0.y; a0.z += v0.z; a0.w += v0.w;
        a1.x += v1.x; a1.y += v1.y; a1.z += v1.z; a1.w += v1.w;
        a2.x += v2.x; a2.y += v2.y; a2.z += v2.z; a2.w += v2.w;
        a3.x += v3.x; a3.y += v3.y; a3.z += v3.z; a3.w += v3.w;
    }
    for (; e < end; ++e) {
        float4 v0 = H4[(size_t)esrc[e] * 32 + l4];
        a0.x += v0.x; a0.y += v0.y; a0.z += v0.z; a0.w += v0.w;
    }
    a0.x += a1.x; a0.y += a1.y; a0.z += a1.z; a0.w += a1.w;
    a2.x += a3.x; a2.y += a3.y; a2.z += a3.z; a2.w += a3.w;
    a0.x += a2.x; a0.y += a2.y; a0.z += a2.z; a0.w += a2.w;
    ((float4*)agg)[(size_t)node * 32 + l4] = a0;
}

// Z[r][c] = (sum_k A[r][k]*WmT[k][c] + bias[c]) * (snorm ? snorm[r] : 1)
// optional per-column sum / sumsq accumulation into colsum[0][c], colsum[1][c]
__global__ __launch_bounds__(256) void gemm_kernel(
    const float* __restrict__ A, const float* __restrict__ WmT,
    const float* __restrict__ bias, const float* __restrict__ snorm,
    float* __restrict__ Z, float* __restrict__ colsum, int nRows)
{
    __shared__ float Ws[KC][128];
    __shared__ float As[TILE_R][KC + 1];
    int tid = threadIdx.x;
    int tx = tid & 15;       // 16 col groups
    int ty = tid >> 4;       // 16 row groups (4 rows each)
    int r0 = blockIdx.x * TILE_R;

    float acc[4][8];
#pragma unroll
    for (int i = 0; i < 4; ++i)
#pragma unroll
        for (int j = 0; j < 8; ++j) acc[i][j] = 0.f;

    for (int k0 = 0; k0 < 128; k0 += KC) {
        {
            const float4* srcv = (const float4*)(WmT + k0 * 128);
            float4* dstv = (float4*)&Ws[0][0];
#pragma unroll
            for (int it = 0; it < 4; ++it) {
                int f4 = tid + it * 256;
                dstv[f4] = srcv[f4];
            }
        }
        {
            int rr = tid >> 3;      // 0..31
            int l8 = tid & 7;       // 0..7
#pragma unroll
            for (int it = 0; it < 2; ++it) {
                int r = rr + it * 32;
                int gr = r0 + r;
                float4 v = make_float4(0.f, 0.f, 0.f, 0.f);
                if (gr < nRows) v = *(const float4*)(A + (size_t)gr * 128 + k0 + l8 * 4);
                As[r][l8 * 4 + 0] = v.x;
                As[r][l8 * 4 + 1] = v.y;
                As[r][l8 * 4 + 2] = v.z;
                As[r][l8 * 4 + 3] = v.w;
            }
        }
        __syncthreads();
#pragma unroll 4
        for (int k = 0; k < KC; ++k) {
            float a0 = As[ty * 4 + 0][k];
            float a1 = As[ty * 4 + 1][k];
            float a2 = As[ty * 4 + 2][k];
            float a3 = As[ty * 4 + 3][k];
            float4 w0 = *(const float4*)&Ws[k][tx * 4];
            float4 w1 = *(const float4*)&Ws[k][64 + tx * 4];
            acc[0][0] += a0 * w0.x; acc[0][1] += a0 * w0.y; acc[0][2] += a0 * w0.z; acc[0][3] += a0 * w0.w;
            acc[0][4] += a0 * w1.x; acc[0][5] += a0 * w1.y; acc[0][6] += a0 * w1.z; acc[0][7] += a0 * w1.w;
            acc[1][0] += a1 * w0.x; acc[1][1] += a1 * w0.y; acc[1][2] += a1 * w0.z; acc[1][3] += a1 * w0.w;
            acc[1][4] += a1 * w1.x; acc[1][5] += a1 * w1.y; acc[1][6] += a1 * w1.z; acc[1][7] += a1 * w1.w;
            acc[2][0] += a2 * w0.x; acc[2][1] += a2 * w0.y; acc[2][2] += a2 * w0.z; acc[2][3] += a2 * w0.w;
            acc[2][4] += a2 * w1.x; acc[2][5] += a2 * w1.y; acc[2][6] += a2 * w1.z; acc[2][7] += a2 * w1.w;
            acc[3][0] += a3 * w0.x; acc[3][1] += a3 * w0.y; acc[3][2] += a3 * w0.z; acc[3][3] += a3 * w0.w;
            acc[3][4] += a3 * w1.x; acc[3][5] += a3 * w1.y; acc[3][6] += a3 * w1.z; acc[3][7] += a3 * w1.w;
        }
        __syncthreads();
    }

    // epilogue
    int c0 = tx * 4;
    float bl[8];
#pragma unroll
    for (int j = 0; j < 4; ++j) {
        bl[j]     = bias[c0 + j];
        bl[4 + j] = bias[64 + c0 + j];
    }
    float cs[8], cq[8];
#pragma unroll
    for (int j = 0; j < 8; ++j) { cs[j] = 0.f; cq[j] = 0.f; }

#pragma unroll
    for (int i = 0; i < 4; ++i) {
        int r = r0 + ty * 4 + i;
        if (r < nRows) {
            float sn = snorm ? snorm[r] : 1.0f;
            float4 o0, o1;
            float v;
            v = (acc[i][0] + bl[0]) * sn; o0.x = v; cs[0] += v; cq[0] += v * v;
            v = (acc[i][1] + bl[1]) * sn; o0.y = v; cs[1] += v; cq[1] += v * v;
            v = (acc[i][2] + bl[2]) * sn; o0.z = v; cs[2] += v; cq[2] += v * v;
            v = (acc[i][3] + bl[3]) * sn; o0.w = v; cs[3] += v; cq[3] += v * v;
            v = (acc[i][4] + bl[4]) * sn; o1.x = v; cs[4] += v; cq[4] += v * v;
            v = (acc[i][5] + bl[5]) * sn; o1.y = v; cs[5] += v; cq[5] += v * v;
            v = (acc[i][6] + bl[6]) * sn; o1.z = v; cs[6] += v; cq[6] += v * v;
            v = (acc[i][7] + bl[7]) * sn; o1.w = v; cs[7] += v; cq[7] += v * v;
            *(float4*)(Z + (size_t)r * 128 + c0)      = o0;
            *(float4*)(Z + (size_t)r * 128 + 64 + c0) = o1;
        }
    }

    if (colsum) {
        float* red = &Ws[0][0];  // 16*128 floats fits in Ws (KC*128)
        for (int round = 0; round < 2; ++round) {
            float* srcp = round ? cq : cs;
#pragma unroll
            for (int j = 0; j < 4; ++j) {
                red[ty * 128 + c0 + j]      = srcp[j];
                red[ty * 128 + 64 + c0 + j] = srcp[4 + j];
            }
            __syncthreads();
            if (tid < 128) {
                float s = 0.f;
#pragma unroll
                for (int t = 0; t < 16; ++t) s += red[t * 128 + tid];
                atomicAdd(&colsum[round * 128 + tid], s);
            }
            __syncthreads();
        }
    }
}

// H += relu((Z - mu)*rsqrt(var+eps)*gamma + beta); BN params computed inline from csum
__global__ __launch_bounds__(256) void apply_kernel(const float* __restrict__ Z,
                                                    const float* __restrict__ csum,
                                                    const float* __restrict__ gamma,
                                                    const float* __restrict__ beta,
                                                    float* __restrict__ H, int n4, int layer) {
    int i = blockIdx.x * 256 + threadIdx.x;
    if (i >= n4) return;
    int c4 = i & 31;
    const float invN = 1.0f / (float)N_NODES;
    float4 s  = ((const float4*)(csum  + layer * 256))[c4];
    float4 q  = ((const float4*)(csum  + layer * 256 + 128))[c4];
    float4 g  = ((const float4*)(gamma + layer * 128))[c4];
    float4 be = ((const float4*)(beta  + layer * 128))[c4];
    float4 z = ((const float4*)Z)[i];
    float4 h = ((float4*)H)[i];
    float mu, var, sc, sh;
    mu = s.x * invN; var = q.x * invN - mu * mu; sc = g.x * rsqrtf(var + BN_EPS); sh = be.x - mu * sc;
    h.x += fmaxf(z.x * sc + sh, 0.f);
    mu = s.y * invN; var = q.y * invN - mu * mu; sc = g.y * rsqrtf(var + BN_EPS); sh = be.y - mu * sc;
    h.y += fmaxf(z.y * sc + sh, 0.f);
    mu = s.z * invN; var = q.z * invN - mu * mu; sc = g.z * rsqrtf(var + BN_EPS); sh = be.z - mu * sc;
    h.z += fmaxf(z.z * sc + sh, 0.f);
    mu = s.w * invN; var = q.w * invN - mu * mu; sc = g.w * rsqrtf(var + BN_EPS); sh = be.w - mu * sc;
    h.w += fmaxf(z.w * sc + sh, 0.f);
    ((float4*)H)[i] = h;
}

// dense per-graph reduction using sorted-gid boundaries
__global__ __launch_bounds__(256) void readout2_kernel(const float* __restrict__ H,
                                                       const int* __restrict__ g_start,
                                                       float* __restrict__ sums) {
    int g     = blockIdx.x / RSPLIT;
    int chunk = blockIdx.x % RSPLIT;
    int beg = g_start[g], end = g_start[g + 1];
    int col  = threadIdx.x & 127;
    int half = threadIdx.x >> 7;
    float acc = 0.f;
    for (int r = beg + chunk * 2 + half; r < end; r += RSPLIT * 2) {
        acc += H[(size_t)r * 128 + col];
    }
    if (acc != 0.f || half == 0)
        atomicAdd(&sums[g * 128 + col], acc);
}

__global__ __launch_bounds__(128) void final_kernel(const float* __restrict__ sums,
                                                    const int* __restrict__ g_start,
                                                    const float* __restrict__ roW,
                                                    const float* __restrict__ rob,
                                                    float* __restrict__ out) {
    __shared__ float row[128];
    int g = blockIdx.x;
    int t = threadIdx.x;
    float c = fmaxf((float)(g_start[g + 1] - g_start[g]), 1.0f);
    row[t] = sums[g * 128 + t] / c;
    __syncthreads();
    if (t < N_CLASSES) {
        float s = rob[t];
        for (int k = 0; k < 128; ++k) s += row[k] * roW[t * 128 + k];
        out[g * N_CLASSES + t] = s;
    }
}

extern "C" void kernel_launch(void* const* d_in, const int* in_sizes, int n_in,
                              void* d_out, int out_size, void* d_ws, size_t ws_size,
                              hipStream_t stream) {
    const float* h0      = (const float*)d_in[0];
    const float* snorm   = (const float*)d_in[1];
    const int*   src     = (const int*)d_in[2];
    const int*   dst     = (const int*)d_in[3];
    const int*   gid     = (const int*)d_in[4];
    const float* embedW  = (const float*)d_in[5];
    const float* embedM  = (const float*)d_in[6];
    const float* embedB  = (const float*)d_in[7];
    const float* layerW  = (const float*)d_in[8];
    const float* layerM  = (const float*)d_in[9];
    const float* layerB  = (const float*)d_in[10];
    const float* gamma   = (const float*)d_in[11];
    const float* beta    = (const float*)d_in[12];
    const float* roW     = (const float*)d_in[13];
    const float* rob     = (const float*)d_in[14];
    float* out = (float*)d_out;

    float* ws   = (float*)d_ws;
    float* wmT  = ws + OFF_WMT;
    float* H    = ws + OFF_H;
    float* Z    = ws + OFF_Z;
    float* AGG  = ws + OFF_AGG;
    float* csum = ws + OFF_CSUM;
    float* sums = ws + OFF_SUMS;
    int*   deg  = (int*)(ws + OFF_DEG);
    int*   offs = (int*)(ws + OFF_OFFS);
    int*   pos  = (int*)(ws + OFF_POS);
    int*   esrc = (int*)(ws + OFF_ESRC);
    int*   gst  = (int*)(ws + OFF_GST);
    int*   bsum = (int*)(ws + OFF_BSUM);
    int*   tot  = (int*)(ws + OFF_TOT);

    // zero: colsum + readout sums + deg (single contiguous region)
    zero_kernel<<<(ZERO_N + 255) / 256, 256, 0, stream>>>((int*)(ws + OFF_ZERO), (int)ZERO_N);
    // masked + transposed weights
    wmask_kernel<<<(5 * 16384 + 255) / 256, 256, 0, stream>>>(embedW, embedM, layerW, layerM, wmT);
    // CSR build (once per call, reused by all 4 layers)
    hist_kernel<<<(N_EDGES + 255) / 256, 256, 0, stream>>>(dst, deg, N_EDGES);
    scan1_kernel<<<SCAN_B, 256, 0, stream>>>(deg, offs, bsum, N_NODES);
    scan2_kernel<<<1, 256, 0, stream>>>(bsum, tot, SCAN_B);
    scan3_kernel<<<SCAN_B, 256, 0, stream>>>(offs, bsum, tot, pos, N_NODES);
    fill_kernel<<<(N_EDGES + 255) / 256, 256, 0, stream>>>(src, dst, pos, esrc, N_EDGES);
    // graph boundaries (sorted gid)
    bounds_kernel<<<(N_NODES + 255) / 256, 256, 0, stream>>>(gid, gst, N_NODES);

    const int gemm_grid = (N_NODES + TILE_R - 1) / TILE_R;
    // embedding: H = h0 @ (embed_W*mask)^T + embed_b
    gemm_kernel<<<gemm_grid, 256, 0, stream>>>(h0, wmT, embedB, nullptr, H, nullptr, N_NODES);

    const int agg_grid = (N_NODES / 2 + 3) / 4;   // 2 nodes/wave, 4 waves/block
    for (int l = 0; l < N_LAYERS; ++l) {
        aggregate_kernel<<<agg_grid, 256, 0, stream>>>(H, offs, esrc, AGG, N_NODES);
        gemm_kernel<<<gemm_grid, 256, 0, stream>>>(AGG, wmT + (1 + l) * 16384,
                                                   layerB + l * 128, snorm,
                                                   Z, csum + l * 256, N_NODES);
        apply_kernel<<<(N_NODES * HID / 4) / 256, 256, 0, stream>>>(
            Z, csum, gamma, beta, H, N_NODES * HID / 4, l);
    }

    readout2_kernel<<<N_GRAPHS * RSPLIT, 256, 0, stream>>>(H, gst, sums);
    final_kernel<<<N_GRAPHS, 128, 0, stream>>>(sums, gst, roW, rob, out);
}